// Round 15
// baseline (196.999 us; speedup 1.0000x reference)
//
#include <hip/hip_runtime.h>

typedef unsigned short u16;
using bf16x8 = __attribute__((ext_vector_type(8))) __bf16;
using f32x4  = __attribute__((ext_vector_type(4))) float;

// SCALE * log2(e): softmax runs in exp2 domain
#define QSCALE 0.18033688011f

#define EXP2F(x) __builtin_amdgcn_exp2f(x)
#define SCHED_FENCE() __builtin_amdgcn_sched_barrier(0)

__device__ __forceinline__ u16 f2bf(float f) {
  union { float f; unsigned int u; } x; x.f = f;
  unsigned int r = x.u + 0x7FFFu + ((x.u >> 16) & 1u);
  return (u16)(r >> 16);
}

__device__ __forceinline__ bf16x8 ld8(const u16* p) {
  return *reinterpret_cast<const bf16x8*>(p);
}

__device__ __forceinline__ void gload16(const void* g, void* l) {
  __builtin_amdgcn_global_load_lds(
      (const __attribute__((address_space(1))) unsigned int*)g,
      (__attribute__((address_space(3))) unsigned int*)l, 16, 0, 0);
}

// 3 activation tensors in one launch; outputs contiguous at out + y*n4*4
__global__ void cast3_f32_to_bf16(const float* __restrict__ a, const float* __restrict__ b,
                                  const float* __restrict__ c, u16* __restrict__ out, int n4) {
  const int y = blockIdx.y;
  const int i = blockIdx.x * 256 + threadIdx.x;
  if (i >= n4) return;
  const float* src = (y == 0) ? a : (y == 1) ? b : c;
  const float4 v = reinterpret_cast<const float4*>(src)[i];
  ushort4 o;
  o.x = f2bf(v.x); o.y = f2bf(v.y); o.z = f2bf(v.z); o.w = f2bf(v.w);
  reinterpret_cast<ushort4*>(out + (size_t)y * n4 * 4)[i] = o;
}

__global__ void cast4_f32_to_bf16(const float* __restrict__ a, const float* __restrict__ b,
                                  const float* __restrict__ c, const float* __restrict__ d,
                                  u16* __restrict__ out, int n4) {
  const int y = blockIdx.y;
  const int i = blockIdx.x * 256 + threadIdx.x;
  if (i >= n4) return;
  const float* src = (y == 0) ? a : (y == 1) ? b : (y == 2) ? c : d;
  const float4 v = reinterpret_cast<const float4*>(src)[i];
  ushort4 o;
  o.x = f2bf(v.x); o.y = f2bf(v.y); o.z = f2bf(v.z); o.w = f2bf(v.w);
  reinterpret_cast<ushort4*>(out + (size_t)y * n4 * 4)[i] = o;
}

// ---- 8-phase 256x256 GEMM core (guide §5 template, BK=64, 8 waves) ----
// C = A[M,K] @ B[N,K]^T, bf16 in, f32 acc. K=1024 fixed (16 K-tiles, 8 iters).
// LDS 128 KiB: A,B double-buffered [2][256][64] bf16, linear, source-pre-swizzled
// (chunk ^= (t>>4)&2 == st_16x32 bit9->bit5) + XOR-16 on fragment reads.
// Stage schedule: half-tile (2 quarters) per phase, 4 phases ahead:
//   ph0: B(buf1) q01  ph1: B(buf1) q23  ph2: A(buf1) q01  ph3: A(buf1) q23
//   ph4: B(buf0) q01  ph5: B(buf0) q23  ph6: A(buf0) q01  ph7: A(buf0) q23
// vmcnt(0) at ph0/ph4 == counted wait (only the needed buffer is outstanding).
__device__ __forceinline__ void gemm8_core(const u16* __restrict__ A, const u16* __restrict__ B,
                                           int by, int bx, f32x4 (&acc)[8][4],
                                           u16 (*lds_a)[16384], u16 (*lds_b)[16384]) {
  const int t = threadIdx.x;
  const int w = t >> 6, lane = t & 63;
  const int wm = w >> 2, wn = w & 3;
  const int fr = lane & 15, lh = lane >> 4;
  const int xr = (fr & 4) << 2;                    // fragment-read XOR (elements)
  const int kch = ((t & 7) ^ ((t >> 4) & 2)) * 8;  // pre-swizzled source chunk

  const u16* ga = A + (size_t)(by * 256 + (t >> 3)) * 1024 + kch;
  const u16* gb = B + (size_t)(bx * 256 + (t >> 3)) * 1024 + kch;

#pragma unroll
  for (int m = 0; m < 8; ++m)
#pragma unroll
    for (int n = 0; n < 4; ++n) acc[m][n] = {0.f, 0.f, 0.f, 0.f};

  // prologue: tile 0 -> buf0 (A+B, 4 quarters each)
#pragma unroll
  for (int q = 0; q < 4; ++q) {
    gload16(ga + (size_t)q * 64 * 1024, &lds_a[0][q * 4096 + w * 512]);
    gload16(gb + (size_t)q * 64 * 1024, &lds_b[0][q * 4096 + w * 512]);
  }

  for (int it = 0; it < 8; ++it) {
    const int ts = 2 * it + 1;          // tile staged into buf1 (consumed ph4-7)
    const int tn = (2 * it + 2) & 15;   // tile staged into buf0 (next iter; wrap unused)
    bf16x8 bfr[4][2];
#pragma unroll
    for (int p = 0; p < 8; ++p) {
      const int b = p >> 2, q = p & 3;
      if (q == 0) { asm volatile("s_waitcnt vmcnt(0)" ::: "memory"); }
      __builtin_amdgcn_s_barrier();
      if (q == 0) {
#pragma unroll
        for (int nn = 0; nn < 4; ++nn)
#pragma unroll
          for (int ks = 0; ks < 2; ++ks)
            bfr[nn][ks] = ld8(&lds_b[b][(wn * 64 + nn * 16 + fr) * 64 + ((ks * 32 + lh * 8) ^ xr)]);
      }
      bf16x8 af[2][2];
#pragma unroll
      for (int mm = 0; mm < 2; ++mm)
#pragma unroll
        for (int ks = 0; ks < 2; ++ks)
          af[mm][ks] = ld8(&lds_a[b][(wm * 128 + q * 32 + mm * 16 + fr) * 64 + ((ks * 32 + lh * 8) ^ xr)]);
      // stage one half-tile (2 quarters), 4 phases ahead of its consumption
      {
        const int tt = (p < 4) ? ts : tn;
        const int db = (p < 4) ? 1 : 0;
        const int q0 = (q & 1) * 2;
        if (q < 2) {
          gload16(gb + (size_t)(q0 + 0) * 64 * 1024 + tt * 64, &lds_b[db][(q0 + 0) * 4096 + w * 512]);
          gload16(gb + (size_t)(q0 + 1) * 64 * 1024 + tt * 64, &lds_b[db][(q0 + 1) * 4096 + w * 512]);
        } else {
          gload16(ga + (size_t)(q0 + 0) * 64 * 1024 + tt * 64, &lds_a[db][(q0 + 0) * 4096 + w * 512]);
          gload16(ga + (size_t)(q0 + 1) * 64 * 1024 + tt * 64, &lds_a[db][(q0 + 1) * 4096 + w * 512]);
        }
      }
      __builtin_amdgcn_s_setprio(1);
#pragma unroll
      for (int nn = 0; nn < 4; ++nn)
#pragma unroll
        for (int mm = 0; mm < 2; ++mm)
#pragma unroll
          for (int ks = 0; ks < 2; ++ks)
            acc[q * 2 + mm][nn] = __builtin_amdgcn_mfma_f32_16x16x32_bf16(
                af[mm][ks], bfr[nn][ks], acc[q * 2 + mm][nn], 0, 0, 0);
      __builtin_amdgcn_s_setprio(0);
    }
  }
}

// Q/K/V projections, 8-phase core. Grid 384 = 8 XCD x 48; z = g>>7.
// z=0: Q * QSCALE. z=1: K per-row chunk XOR. z=2: V^T + PV key perm + XOR.
__global__ __launch_bounds__(512)
void gemm8_qkv(const u16* __restrict__ Aall, const u16* __restrict__ Ball,
               u16* __restrict__ Call) {
  __shared__ alignas(16) u16 lds_a[2][16384];
  __shared__ alignas(16) u16 lds_b[2][16384];
  const int g = (blockIdx.x & 7) * 48 + (blockIdx.x >> 3);
  const int z = g >> 7, r7 = g & 127;
  const int by = r7 >> 2, bx = r7 & 3;
  const u16* A = Aall + (size_t)z * 8192 * 1024;
  const u16* B = Ball + (size_t)z * 1024 * 1024;
  u16* C = Call + (size_t)z * 8192 * 1024;

  f32x4 acc[8][4];
  gemm8_core(A, B, by, bx, acc, lds_a, lds_b);

  const int t = threadIdx.x;
  const int w = t >> 6, lane = t & 63;
  const int wm = w >> 2, wn = w & 3;
  const int er = (lane >> 4) * 4, ec = lane & 15;
#pragma unroll
  for (int m = 0; m < 8; ++m)
#pragma unroll
    for (int nn = 0; nn < 4; ++nn) {
      const size_t row = (size_t)by * 256 + wm * 128 + m * 16 + er;
      const size_t col = (size_t)bx * 256 + wn * 64 + nn * 16 + ec;
      if (z == 0) {
#pragma unroll
        for (int rr = 0; rr < 4; ++rr)
          C[(row + rr) * 1024 + col] = f2bf(acc[m][nn][rr] * QSCALE);
      } else if (z == 1) {
        // K: swizzle dim chunk (8 dims = 16B) within head by key&7
#pragma unroll
        for (int rr = 0; rr < 4; ++rr) {
          const size_t n = row + rr;
          const size_t colswz = (col & ~(size_t)63) | ((col & 63) ^ ((n & 7) << 3));
          C[n * 1024 + colswz] = f2bf(acc[m][nn][rr]);
        }
      } else {
        // V^T per head: PV key permutation + key-chunk XOR by dim&7.
        ushort4 o4;
        o4.x = f2bf(acc[m][nn][0]); o4.y = f2bf(acc[m][nn][1]);
        o4.z = f2bf(acc[m][nn][2]); o4.w = f2bf(acc[m][nn][3]);
        const size_t nloc = row & 2047;
        const size_t d = col & 63;
        size_t pos = (nloc & ~(size_t)31) | (((nloc >> 2) & 3) << 3) |
                     (((nloc >> 4) & 1) << 2) | (nloc & 3);
        pos ^= (d & 7) << 3;
        const size_t idx = (((row >> 11) * 16 + (col >> 6)) * 64 + d) * 2048 + pos;
        *reinterpret_cast<ushort4*>(&C[idx]) = o4;
      }
    }
}

// Out-projection, 8-phase core: f32 out + bias. Grid 128 = 8 XCD x 16.
__global__ __launch_bounds__(512)
void gemm8_out(const u16* __restrict__ A, const u16* __restrict__ B,
               float* __restrict__ Cf, const float* __restrict__ bias) {
  __shared__ alignas(16) u16 lds_a[2][16384];
  __shared__ alignas(16) u16 lds_b[2][16384];
  const int g = (blockIdx.x & 7) * 16 + (blockIdx.x >> 3);
  const int by = g >> 2, bx = g & 3;

  f32x4 acc[8][4];
  gemm8_core(A, B, by, bx, acc, lds_a, lds_b);

  const int t = threadIdx.x;
  const int w = t >> 6, lane = t & 63;
  const int wm = w >> 2, wn = w & 3;
  const int er = (lane >> 4) * 4, ec = lane & 15;
#pragma unroll
  for (int m = 0; m < 8; ++m)
#pragma unroll
    for (int nn = 0; nn < 4; ++nn) {
      const size_t row = (size_t)by * 256 + wm * 128 + m * 16 + er;
      const size_t col = (size_t)bx * 256 + wn * 64 + nn * 16 + ec;
#pragma unroll
      for (int rr = 0; rr < 4; ++rr)
        Cf[(row + rr) * 1024 + col] = acc[m][nn][rr] + bias[col];
    }
}

// Flash attention v9 (race-hardened, proven r13/r14 — unchanged): 512 threads,
// QBLK=256, swapped QK^T, raw-exp2 softmax, ones-column MFMA row-sum, gload_lds
// dbuf with explicit vmcnt drain + sched fences.
__global__ __launch_bounds__(512)
void flash_attn(const u16* __restrict__ Q, const u16* __restrict__ Km,
                const u16* __restrict__ Vt, u16* __restrict__ O) {
  const int o_blk = (blockIdx.x & 7) * 64 + (blockIdx.x >> 3);
  const int qt = o_blk & 7, h = (o_blk >> 3) & 15, b = o_blk >> 7;
  const int t = threadIdx.x;
  const int w = t >> 6, lane = t & 63;
  const int l16 = lane & 15, lh = lane >> 4;

  __shared__ alignas(16) u16 kt_lds[2][64][64];
  __shared__ alignas(16) u16 vt_lds[2][64][64];

  const size_t base_qk = ((size_t)b * 2048) * 1024 + (size_t)h * 64;
  const size_t base_vt = ((size_t)(b * 16 + h)) * 64 * 2048;

  bf16x8 qf[2][2];
#pragma unroll
  for (int g = 0; g < 2; ++g) {
    const size_t qrow = (size_t)qt * 256 + (w * 2 + g) * 16 + l16;
    const u16* qp = Q + base_qk + qrow * 1024 + lh * 8;
    qf[g][0] = ld8(qp);
    qf[g][1] = ld8(qp + 32);
  }

  bf16x8 vones;
#pragma unroll
  for (int i = 0; i < 8; ++i) vones[i] = (__bf16)1.0f;

  f32x4 o_acc[2][4];
  f32x4 o_sum[2];
#pragma unroll
  for (int g = 0; g < 2; ++g) {
#pragma unroll
    for (int j = 0; j < 4; ++j) o_acc[g][j] = {0.f, 0.f, 0.f, 0.f};
    o_sum[g] = {0.f, 0.f, 0.f, 0.f};
  }

  const int srow = t >> 3;
  const int schk = (t & 7) * 8;
  const u16* kg = Km + base_qk + (size_t)srow * 1024 + schk;
  const u16* vg = Vt + base_vt + (size_t)srow * 2048 + schk;
  u16* kl0 = &kt_lds[0][0][0] + w * 512;
  u16* kl1 = &kt_lds[1][0][0] + w * 512;
  u16* vl0 = &vt_lds[0][0][0] + w * 512;
  u16* vl1 = &vt_lds[1][0][0] + w * 512;

  gload16(kg, kl0);
  gload16(vg, vl0);

  const int xo = (l16 & 7) << 3;

  for (int it = 0; it < 32; ++it) {
    const int cur = it & 1;
    asm volatile("s_waitcnt vmcnt(0)" ::: "memory");
    SCHED_FENCE();
    __syncthreads();
    SCHED_FENCE();

    if (it != 31) {
      const int nkv = (it + 1) * 64;
      gload16(kg + (size_t)nkv * 1024, cur ? kl0 : kl1);
      gload16(vg + nkv, cur ? vl0 : vl1);
    }
    SCHED_FENCE();

    f32x4 s[2][4];
#pragma unroll
    for (int g = 0; g < 2; ++g)
#pragma unroll
      for (int j = 0; j < 4; ++j) s[g][j] = {0.f, 0.f, 0.f, 0.f};
    __builtin_amdgcn_s_setprio(1);
#pragma unroll
    for (int j = 0; j < 4; ++j)
#pragma unroll
      for (int ks = 0; ks < 2; ++ks) {
        bf16x8 kf = ld8(&kt_lds[cur][j * 16 + l16][(ks * 32 + lh * 8) ^ xo]);
        s[0][j] = __builtin_amdgcn_mfma_f32_16x16x32_bf16(kf, qf[0][ks], s[0][j], 0, 0, 0);
        s[1][j] = __builtin_amdgcn_mfma_f32_16x16x32_bf16(kf, qf[1][ks], s[1][j], 0, 0, 0);
      }
    __builtin_amdgcn_s_setprio(0);

    bf16x8 pa[2][2];
#pragma unroll
    for (int g = 0; g < 2; ++g)
#pragma unroll
      for (int j = 0; j < 4; ++j)
#pragma unroll
        for (int r = 0; r < 4; ++r)
          s[g][j][r] = EXP2F(s[g][j][r]);
#pragma unroll
    for (int g = 0; g < 2; ++g)
#pragma unroll
      for (int c = 0; c < 2; ++c)
#pragma unroll
        for (int i = 0; i < 8; ++i)
          pa[g][c][i] = (__bf16)s[g][2 * c + (i >> 2)][i & 3];

    __builtin_amdgcn_s_setprio(1);
#pragma unroll
    for (int c = 0; c < 2; ++c) {
      o_sum[0] = __builtin_amdgcn_mfma_f32_16x16x32_bf16(pa[0][c], vones, o_sum[0], 0, 0, 0);
      o_sum[1] = __builtin_amdgcn_mfma_f32_16x16x32_bf16(pa[1][c], vones, o_sum[1], 0, 0, 0);
#pragma unroll
      for (int jd = 0; jd < 4; ++jd) {
        bf16x8 vf = ld8(&vt_lds[cur][jd * 16 + l16][(c * 32 + lh * 8) ^ xo]);
        o_acc[0][jd] = __builtin_amdgcn_mfma_f32_16x16x32_bf16(pa[0][c], vf, o_acc[0][jd], 0, 0, 0);
        o_acc[1][jd] = __builtin_amdgcn_mfma_f32_16x16x32_bf16(pa[1][c], vf, o_acc[1][jd], 0, 0, 0);
      }
    }
    __builtin_amdgcn_s_setprio(0);
  }

#pragma unroll
  for (int g = 0; g < 2; ++g) {
    float linv[4];
#pragma unroll
    for (int r = 0; r < 4; ++r) linv[r] = 1.0f / o_sum[g][r];
    const size_t orow0 = (size_t)b * 2048 + (size_t)qt * 256 + (w * 2 + g) * 16;
#pragma unroll
    for (int jd = 0; jd < 4; ++jd) {
      const int col = h * 64 + jd * 16 + l16;
#pragma unroll
      for (int r = 0; r < 4; ++r)
        O[(orow0 + lh * 4 + r) * 1024 + col] = f2bf(o_acc[g][jd][r] * linv[r]);
    }
  }
}

extern "C" void kernel_launch(void* const* d_in, const int* in_sizes, int n_in,
                              void* d_out, int out_size, void* d_ws, size_t ws_size,
                              hipStream_t stream) {
  const float* xq = (const float*)d_in[0];
  const float* xk = (const float*)d_in[1];
  const float* xv = (const float*)d_in[2];
  const float* Wq = (const float*)d_in[3];
  const float* Wk = (const float*)d_in[4];
  const float* Wv = (const float*)d_in[5];
  const float* Wo = (const float*)d_in[6];
  const float* bo = (const float*)d_in[7];
  float* out = (float*)d_out;

  const size_t X = (size_t)8192 * 1024;
  const size_t W = (size_t)1024 * 1024;

  u16* p = (u16*)d_ws;
  u16* x_bf  = p; p += 3 * X;          // xq | xk | xv (contiguous)
  u16* w_bf  = p; p += 4 * W;          // Wq | Wk | Wv | Wo
  u16* qkv   = p; p += 3 * X;          // Q | K(swz) | V^T(swz)
  u16* attn_bf = x_bf;                  // x_bf dead after projections; reuse

  dim3 blk(256);
  cast3_f32_to_bf16<<<dim3(8192, 3), blk, 0, stream>>>(xq, xk, xv, x_bf, (int)(X / 4));
  cast4_f32_to_bf16<<<dim3(1024, 4), blk, 0, stream>>>(Wq, Wk, Wv, Wo, w_bf, (int)(W / 4));

  gemm8_qkv<<<dim3(384), dim3(512), 0, stream>>>(x_bf, w_bf, qkv);

  flash_attn<<<dim3(512), dim3(512), 0, stream>>>(qkv, qkv + X, qkv + 2 * X, attn_bf);

  gemm8_out<<<dim3(128), dim3(512), 0, stream>>>(attn_bf, w_bf + 3 * W, out, bo);
}